// Round 20
// baseline (141.632 us; speedup 1.0000x reference)
//
#include <hip/hip_runtime.h>
#include <hip/hip_bf16.h>

// MDTA (multi-head cross attention with l2-normed q/k) for MI355X.
// B=8, N=4096, Ktok=256, C=512, H=8, D=64. Inputs f32, output f32.
//
// R8 187.9 -> R14 134.9 -> R16 127.6 -> R18 131.8 -> R19 127.7 (attn 42.3,
// fragment-image producer layout: coalesced linear staging, conflict-free
// reads). R20: QBLK=128, 2 q-tiles per wave (R17 retry on correct substrate:
// the 11M-conflict layout and VGPR are fixed/irrelevant now). K/V staging
// amortized 2x, K ds_reads feed 2 MFMAs, 2 softmax chains of ILP, 2048 blocks.
//
// Pipeline: cvt_all -> proj<KV> -> proj<Q> -> attn_fused -> out_gemm.

typedef __bf16 bf16;
typedef __attribute__((ext_vector_type(8))) __bf16 bf16x8;
typedef __attribute__((ext_vector_type(4))) float f32x4;

#if __has_builtin(__builtin_amdgcn_exp2f)
#define EXP2(x) __builtin_amdgcn_exp2f(x)
#else
#define EXP2(x) exp2f(x)
#endif

__device__ __forceinline__ void gload_lds16(const void* g, void* l) {
  __builtin_amdgcn_global_load_lds(
      (__attribute__((address_space(1))) void*)g,
      (__attribute__((address_space(3))) void*)l, 16, 0, 0);
}

__device__ __forceinline__ unsigned pack2(float a, float b) {
  unsigned short x = __builtin_bit_cast(unsigned short, (bf16)a);
  unsigned short y = __builtin_bit_cast(unsigned short, (bf16)b);
  return (unsigned)x | ((unsigned)y << 16);
}

// ---------------------------------------------------------------------------
// Convert X (2097152 chunks), S (131072), Wq/Wk/Wv/Wo (32768 each) to bf16.
// ---------------------------------------------------------------------------
__global__ __launch_bounds__(256) void cvt_all(
    const float* __restrict__ X, const float* __restrict__ S,
    const float* __restrict__ Wq, const float* __restrict__ Wk,
    const float* __restrict__ Wv, const float* __restrict__ Wo,
    bf16* __restrict__ Xb, bf16* __restrict__ Sb, bf16* __restrict__ Wqb,
    bf16* __restrict__ Wkb, bf16* __restrict__ Wvb, bf16* __restrict__ Wob) {
  int i = blockIdx.x * 256 + threadIdx.x;
  const float* src;
  bf16* dst;
  int r;
  if (i < 2097152) {
    src = X; dst = Xb; r = i;
  } else if (i < 2228224) {
    src = S; dst = Sb; r = i - 2097152;
  } else {
    int j = i - 2228224;
    int w = j >> 15;
    r = j & 32767;
    src = (w == 0) ? Wq : (w == 1) ? Wk : (w == 2) ? Wv : Wo;
    dst = (w == 0) ? Wqb : (w == 1) ? Wkb : (w == 2) ? Wvb : Wob;
  }
  float4 a = *(const float4*)(src + (size_t)r * 8);
  float4 b = *(const float4*)(src + (size_t)r * 8 + 4);
  uint4 v;
  v.x = pack2(a.x, a.y);
  v.y = pack2(a.z, a.w);
  v.z = pack2(b.x, b.y);
  v.w = pack2(b.z, b.w);
  *(uint4*)(dst + (size_t)r * 8) = v;
}

// ---------------------------------------------------------------------------
// Projections. 128x128 tile, BK=32, 16 stages, depth-3 gload_lds pipeline.
// PHASE 0 (grid 1024): Q = l2norm(X@Wq^T)*temp*log2e -> Qfrag images.
// PHASE 1 (grid 128):  Kn = l2norm(S@Wk^T) -> Kfrag; V = S@Wv^T -> Vfrag.
// Fragment image per (b,h): 16B unit u = instr*64 + lane holds
//   Q/K: row (x*16 + lane&15), d-slice (s*32 + (lane>>4)*8), instr = x*2+s
//   V:   V^T row d = ni*16 + (lane&15), t-slice (ks*32 + (lane>>4)*8),
//        instr = ks*4 + ni
// ---------------------------------------------------------------------------
template <int PHASE>
__global__ __launch_bounds__(256) void proj_all(
    const bf16* __restrict__ Xb, const bf16* __restrict__ Sb,
    const bf16* __restrict__ Wqb, const bf16* __restrict__ Wkb,
    const bf16* __restrict__ Wvb, const float* __restrict__ temp,
    bf16* __restrict__ Qf, bf16* __restrict__ Kf, bf16* __restrict__ Vf) {
  __shared__ __align__(16) char smem[49152];  // 3x(As 8KB + Bs 8KB)

  const bf16* A;
  const bf16* W;
  int m0, n0, kind;
  if (PHASE == 0) {
    const int lg = (blockIdx.x & 7) * 128 + (blockIdx.x >> 3);  // 1024
    kind = 0; A = Xb; W = Wqb;
    m0 = (lg >> 2) * 128;
    n0 = (lg & 3) * 128;
  } else {
    const int lg = (blockIdx.x & 7) * 16 + (blockIdx.x >> 3);  // 128
    if (lg < 64) {
      kind = 1; A = Sb; W = Wkb;
      m0 = (lg >> 2) * 128;
      n0 = (lg & 3) * 128;
    } else {
      kind = 2; A = Sb; W = Wvb;
      m0 = ((lg - 64) >> 2) * 128;
      n0 = ((lg - 64) & 3) * 128;
    }
  }

  const int tid = threadIdx.x;
  const int wid = tid >> 6, lane = tid & 63;
  const int wr = wid >> 1, wc = wid & 1;
  const int g = lane >> 4, c16 = lane & 15;
  const int r0 = tid >> 2, cc0 = tid & 3;
  const int r1 = (256 + tid) >> 2, cc1 = tid & 3;
  const int dst0 = (tid & ~63) * 16, dst1 = (256 + (tid & ~63)) * 16;

  f32x4 acc[4][4] = {};

#define PSTAGE(kb, buf)                                                     \
  {                                                                         \
    char* as = smem + (buf) * 8192;                                         \
    char* bs = smem + 24576 + (buf) * 8192;                                 \
    gload_lds16(A + (size_t)(m0 + r0) * 512 + (kb) + cc0 * 8, as + dst0);   \
    gload_lds16(A + (size_t)(m0 + r1) * 512 + (kb) + cc1 * 8, as + dst1);   \
    gload_lds16(W + (size_t)(n0 + r0) * 512 + (kb) + cc0 * 8, bs + dst0);   \
    gload_lds16(W + (size_t)(n0 + r1) * 512 + (kb) + cc1 * 8, bs + dst1);   \
  }

#define PCOMPUTE(buf)                                                       \
  {                                                                         \
    const bf16* as = (const bf16*)(smem + (buf) * 8192);                    \
    const bf16* bs = (const bf16*)(smem + 24576 + (buf) * 8192);            \
    bf16x8 af[4], bfr[4];                                                   \
    _Pragma("unroll") for (int mi = 0; mi < 4; ++mi) af[mi] =               \
        *(const bf16x8*)(as + (wr * 64 + mi * 16 + c16) * 32 + g * 8);      \
    _Pragma("unroll") for (int ni = 0; ni < 4; ++ni) bfr[ni] =              \
        *(const bf16x8*)(bs + (wc * 64 + ni * 16 + c16) * 32 + g * 8);      \
    _Pragma("unroll") for (int mi = 0; mi < 4; ++mi)                        \
        _Pragma("unroll") for (int ni = 0; ni < 4; ++ni) acc[mi][ni] =      \
            __builtin_amdgcn_mfma_f32_16x16x32_bf16(af[mi], bfr[ni],        \
                                                    acc[mi][ni], 0, 0, 0);  \
  }

  PSTAGE(0, 0);
  PSTAGE(32, 1);
  int bufc = 0;
  for (int t = 0; t < 14; ++t) {
    int bufn = bufc + 2;
    if (bufn >= 3) bufn -= 3;
    PSTAGE((t + 2) * 32, bufn);
    asm volatile("s_waitcnt vmcnt(8)" ::: "memory");
    __builtin_amdgcn_s_barrier();
    PCOMPUTE(bufc);
    __builtin_amdgcn_s_barrier();
    if (++bufc == 3) bufc = 0;
  }
  asm volatile("s_waitcnt vmcnt(4)" ::: "memory");
  __builtin_amdgcn_s_barrier();
  PCOMPUTE(bufc);
  __builtin_amdgcn_s_barrier();
  if (++bufc == 3) bufc = 0;
  asm volatile("s_waitcnt vmcnt(0)" ::: "memory");
  __builtin_amdgcn_s_barrier();
  PCOMPUTE(bufc);

  __syncthreads();  // release K-loop LDS for epilogue re-tile

  // ---- epilogue. C/D frag: col = lane&15, row = (lane>>4)*4 + j   [m89]
  if (kind != 2) {
    // l2norm (Q also scaled by temp[h]*log2e) -> LDS re-tile -> fragment img
    const float sc =
        (kind == 0) ? temp[(n0 + wc * 64) >> 6] * 1.44269504088896f : 1.0f;
    char* eps = smem + wid * 8192;  // wave-private 64x64 bf16 tile
#pragma unroll
    for (int mi = 0; mi < 4; ++mi) {
      float ss[4];
#pragma unroll
      for (int j = 0; j < 4; ++j) {
        float s = 0.f;
#pragma unroll
        for (int ni = 0; ni < 4; ++ni) {
          float v = acc[mi][ni][j];
          s += v * v;
        }
        ss[j] = s;
      }
#pragma unroll
      for (int msk = 1; msk < 16; msk <<= 1)
#pragma unroll
        for (int j = 0; j < 4; ++j) ss[j] += __shfl_xor(ss[j], msk, 64);
      float inv[4];
#pragma unroll
      for (int j = 0; j < 4; ++j)
        inv[j] = rsqrtf(fmaxf(ss[j], 1e-24f)) * sc;
#pragma unroll
      for (int ni = 0; ni < 4; ++ni)
#pragma unroll
        for (int j = 0; j < 4; ++j) {
          int row = mi * 16 + g * 4 + j, col = ni * 16 + c16;
          int off = (row * 128 + col * 2) ^ ((row & 7) << 4);
          *(bf16*)(eps + off) = (bf16)(acc[mi][ni][j] * inv[j]);
        }
    }
    asm volatile("s_waitcnt lgkmcnt(0)" ::: "memory");
    __builtin_amdgcn_sched_barrier(0);
#pragma unroll
    for (int it = 0; it < 8; ++it) {
      int c = it * 64 + lane;
      int row = c >> 3, ch = c & 7;
      int off = (row * 128 + ch * 16) ^ ((row & 7) << 4);
      bf16x8 v = *(const bf16x8*)(eps + off);
      int rg = m0 + wr * 64 + row;
      int cg = n0 + wc * 64 + ch * 8;
      int hh = cg >> 6, d0 = cg & 63;
      if (kind == 0) {
        int bb = rg >> 12, qr = rg & 4095;
        int unit = ((qr >> 4) * 2 + (d0 >> 5)) * 64 + ((d0 & 31) >> 3) * 16 +
                   (qr & 15);
        *(bf16x8*)(Qf + (((size_t)(bb * 8 + hh)) << 18) + unit * 8) = v;
      } else {
        int bb = rg >> 8, tt = rg & 255;
        int unit = ((tt >> 4) * 2 + (d0 >> 5)) * 64 + ((d0 & 31) >> 3) * 16 +
                   (tt & 15);
        *(bf16x8*)(Kf + (((size_t)(bb * 8 + hh)) << 14) + unit * 8) = v;
      }
    }
  } else {
    // V fragment store: 4 consecutive tokens at one (h,d) -> 8B into unit
#pragma unroll
    for (int mi = 0; mi < 4; ++mi) {
      int m = m0 + wr * 64 + mi * 16 + g * 4;  // +j
      int bb = m >> 8, tt = m & 255;
#pragma unroll
      for (int ni = 0; ni < 4; ++ni) {
        int col = n0 + wc * 64 + ni * 16 + c16;
        int hh = col >> 6, d = col & 63;
        int unit = ((tt >> 5) * 4 + (d >> 4)) * 64 + ((tt >> 3) & 3) * 16 +
                   (d & 15);
        uint2 v;
        v.x = pack2(acc[mi][ni][0], acc[mi][ni][1]);
        v.y = pack2(acc[mi][ni][2], acc[mi][ni][3]);
        *(uint2*)(Vf + (((size_t)(bb * 8 + hh)) << 14) + unit * 8 +
                  (tt & 7)) = v;
      }
    }
  }
#undef PSTAGE
#undef PCOMPUTE
}

// ---------------------------------------------------------------------------
// out = X + O @ Wo^T, f32 output. Depth-3 pipeline + f32x4 re-tiled epilogue.
// ---------------------------------------------------------------------------
__global__ __launch_bounds__(256) void out_gemm(
    const bf16* __restrict__ O, const bf16* __restrict__ Wob,
    const float* __restrict__ Xres, float* __restrict__ out) {
  __shared__ __align__(16) char smem[49152];

  const int lg = (blockIdx.x & 7) * 128 + (blockIdx.x >> 3);  // XCD swizzle
  const int m0 = (lg >> 2) * 128, n0 = (lg & 3) * 128;

  const int tid = threadIdx.x;
  const int wid = tid >> 6, lane = tid & 63;
  const int wr = wid >> 1, wc = wid & 1;
  const int g = lane >> 4, c16 = lane & 15;
  const int r0 = tid >> 2, cc0 = tid & 3;
  const int r1 = (256 + tid) >> 2, cc1 = tid & 3;
  const int dst0 = (tid & ~63) * 16, dst1 = (256 + (tid & ~63)) * 16;

  f32x4 acc[4][4] = {};

#define OSTAGE(kb, buf)                                                      \
  {                                                                          \
    char* as = smem + (buf) * 8192;                                          \
    char* bs = smem + 24576 + (buf) * 8192;                                  \
    gload_lds16(O + (size_t)(m0 + r0) * 512 + (kb) + cc0 * 8, as + dst0);    \
    gload_lds16(O + (size_t)(m0 + r1) * 512 + (kb) + cc1 * 8, as + dst1);    \
    gload_lds16(Wob + (size_t)(n0 + r0) * 512 + (kb) + cc0 * 8, bs + dst0);  \
    gload_lds16(Wob + (size_t)(n0 + r1) * 512 + (kb) + cc1 * 8, bs + dst1);  \
  }

#define OCOMPUTE(buf)                                                       \
  {                                                                         \
    const bf16* as = (const bf16*)(smem + (buf) * 8192);                    \
    const bf16* bs = (const bf16*)(smem + 24576 + (buf) * 8192);            \
    bf16x8 af[4], bfr[4];                                                   \
    _Pragma("unroll") for (int mi = 0; mi < 4; ++mi) af[mi] =               \
        *(const bf16x8*)(as + (wr * 64 + mi * 16 + c16) * 32 + g * 8);      \
    _Pragma("unroll") for (int ni = 0; ni < 4; ++ni) bfr[ni] =              \
        *(const bf16x8*)(bs + (wc * 64 + ni * 16 + c16) * 32 + g * 8);      \
    _Pragma("unroll") for (int mi = 0; mi < 4; ++mi)                        \
        _Pragma("unroll") for (int ni = 0; ni < 4; ++ni) acc[mi][ni] =      \
            __builtin_amdgcn_mfma_f32_16x16x32_bf16(af[mi], bfr[ni],        \
                                                    acc[mi][ni], 0, 0, 0);  \
  }

  OSTAGE(0, 0);
  OSTAGE(32, 1);
  int bufc = 0;
  for (int t = 0; t < 14; ++t) {
    int bufn = bufc + 2;
    if (bufn >= 3) bufn -= 3;
    OSTAGE((t + 2) * 32, bufn);
    asm volatile("s_waitcnt vmcnt(8)" ::: "memory");
    __builtin_amdgcn_s_barrier();
    OCOMPUTE(bufc);
    __builtin_amdgcn_s_barrier();
    if (++bufc == 3) bufc = 0;
  }
  asm volatile("s_waitcnt vmcnt(4)" ::: "memory");
  __builtin_amdgcn_s_barrier();
  OCOMPUTE(bufc);
  __builtin_amdgcn_s_barrier();
  if (++bufc == 3) bufc = 0;
  asm volatile("s_waitcnt vmcnt(0)" ::: "memory");
  __builtin_amdgcn_s_barrier();
  OCOMPUTE(bufc);

  __syncthreads();  // release K-loop LDS for f32 re-tile

  // Epilogue: 2 passes x (32 rows x 64 cols f32) per wave, swizzled LDS,
  // then float4 X-load + add + float4 store (full-line writes).
  char* eps = smem + wid * 8192;
#pragma unroll
  for (int p = 0; p < 2; ++p) {
#pragma unroll
    for (int mm = 0; mm < 2; ++mm)
#pragma unroll
      for (int ni = 0; ni < 4; ++ni)
#pragma unroll
        for (int j = 0; j < 4; ++j) {
          int row = mm * 16 + g * 4 + j, col = ni * 16 + c16;
          int off = (row * 256 + col * 4) ^ ((row & 7) << 4);
          *(float*)(eps + off) = acc[p * 2 + mm][ni][j];
        }
    asm volatile("s_waitcnt lgkmcnt(0)" ::: "memory");
    __builtin_amdgcn_sched_barrier(0);
#pragma unroll
    for (int it = 0; it < 8; ++it) {
      int c = it * 64 + lane;
      int row = c >> 4, ch = c & 15;
      int off = (row * 256 + ch * 16) ^ ((row & 7) << 4);
      float4 v = *(const float4*)(eps + off);
      size_t gr = (size_t)(m0 + wr * 64 + p * 32 + row) * 512 + n0 +
                  wc * 64 + ch * 4;
      float4 x = *(const float4*)(Xres + gr);
      v.x += x.x;
      v.y += x.y;
      v.z += x.z;
      v.w += x.w;
      *(float4*)(out + gr) = v;
    }
    asm volatile("s_waitcnt lgkmcnt(0)" ::: "memory");
    __builtin_amdgcn_sched_barrier(0);
  }
#undef OSTAGE
#undef OCOMPUTE
}

// ---------------------------------------------------------------------------
// Fused attention. Block = (b, h, 128 q-rows), 256 thr = 4 waves, 64 KB LDS
// -> 2 blocks/CU. Wave w owns q-tiles {n0 + w*16} and {n0 + 64 + w*16}.
// K/V/Q in fragment image order: linear coalesced staging, conflict-free
// lane-contiguous ds_reads; each K fragment read feeds TWO MFMAs.
//   [0,32768)     K frags (32 instr) -> dead after QK^T -> P slices (8KB/wave,
//                 reused sequentially for tile 0 then tile 1)
//   [32768,65536) V frags (32 instr)
// Q pre-scaled by temp*log2e -> exp2 softmax, 1/sum deferred to oacc.
// ---------------------------------------------------------------------------
__global__ __launch_bounds__(256) void attn_fused(
    const bf16* __restrict__ Qf, const bf16* __restrict__ Kf,
    const bf16* __restrict__ Vf, bf16* __restrict__ O) {
  __shared__ __align__(16) char smem[65536];

  const int tid = threadIdx.x;
  const int w = tid >> 6, lane = tid & 63;
  const int g = lane >> 4, c16 = lane & 15;
  // XCD swizzle: 2048 = 8 XCDs x 256; blocks sharing (b,h) -> same XCD L2.
  const int lg = (blockIdx.x & 7) * 256 + (blockIdx.x >> 3);
  const int nt = lg & 31, h = (lg >> 5) & 7, b = lg >> 8;
  const int n0 = nt * 128;

  const bf16* Kimg = Kf + (((size_t)(b * 8 + h)) << 14);
  const bf16* Vimg = Vf + (((size_t)(b * 8 + h)) << 14);
  const bf16* Qimg = Qf + (((size_t)(b * 8 + h)) << 18);

  // ---- stage K, V: purely linear (fragment images match LDS layout)
#pragma unroll
  for (int it = 0; it < 8; ++it) {
    int base = it * 256 + w * 64;  // wave-uniform 16B-unit base
    gload_lds16(Kimg + (size_t)(base + lane) * 8, smem + base * 16);
    gload_lds16(Vimg + (size_t)(base + lane) * 8, smem + 32768 + base * 16);
  }
  // ---- Q fragments direct to registers, both q-tiles (coalesced)
  bf16x8 qf0[2], qf1[2];
  {
    int u0 = (nt * 8 + w) * 2;        // tile 0: rows n0 + w*16 ..
    int u1 = (nt * 8 + 4 + w) * 2;    // tile 1: rows n0 + 64 + w*16 ..
    qf0[0] = *(const bf16x8*)(Qimg + (size_t)((u0 + 0) * 64 + lane) * 8);
    qf0[1] = *(const bf16x8*)(Qimg + (size_t)((u0 + 1) * 64 + lane) * 8);
    qf1[0] = *(const bf16x8*)(Qimg + (size_t)((u1 + 0) * 64 + lane) * 8);
    qf1[1] = *(const bf16x8*)(Qimg + (size_t)((u1 + 1) * 64 + lane) * 8);
  }
  __syncthreads();  // drains gload_lds (vmcnt) + barrier

  // ---- QK^T both tiles; each kf read feeds 2 MFMAs
  f32x4 sacc0[16] = {}, sacc1[16] = {};
#pragma unroll
  for (int mi = 0; mi < 16; ++mi) {
#pragma unroll
    for (int s = 0; s < 2; ++s) {
      bf16x8 kf = *(const bf16x8*)(smem + ((mi * 2 + s) * 64 + lane) * 16);
      sacc0[mi] = __builtin_amdgcn_mfma_f32_16x16x32_bf16(kf, qf0[s],
                                                          sacc0[mi], 0, 0, 0);
      sacc1[mi] = __builtin_amdgcn_mfma_f32_16x16x32_bf16(kf, qf1[s],
                                                          sacc1[mi], 0, 0, 0);
    }
  }

  // ---- softmax: two independent chains (temp*log2e pre-folded into Q)
  float mxa[4] = {-1e30f, -1e30f, -1e30f, -1e30f};
  float mxb[4] = {-1e30f, -1e30f, -1e30f, -1e30f};
#pragma unroll
  for (int mi = 0; mi < 16; ++mi)
#pragma unroll
    for (int j = 0; j < 4; ++j) {
      mxa[j] = fmaxf(mxa[j], sacc0[mi][j]);
      mxb[j] = fmaxf(mxb[j], sacc1[mi][j]);
    }
  float mx0 = fmaxf(fmaxf(mxa[0], mxa[1]), fmaxf(mxa[2], mxa[3]));
  float mx1 = fmaxf(fmaxf(mxb[0], mxb[1]), fmaxf(mxb[2], mxb[3]));
  mx0 = fmaxf(mx0, __shfl_xor(mx0, 16, 64));
  mx0 = fmaxf(mx0, __shfl_xor(mx0, 32, 64));
  mx1 = fmaxf(mx1, __shfl_xor(mx1, 16, 64));
  mx1 = fmaxf(mx1, __shfl_xor(mx1, 32, 64));
  float sa[4] = {0.f, 0.f, 0.f, 0.f}, sb[4] = {0.f, 0.f, 0.f, 0.f};
#pragma unroll
  for (int mi = 0; mi < 16; ++mi)
#pragma unroll
    for (int j = 0; j < 4; ++j) {
      float p0 = EXP2(sacc0[mi][j] - mx0);
      float p1 = EXP2(sacc1[mi][j] - mx1);
      sacc0[mi][j] = p0;
      sacc1[mi][j] = p1;
      sa[j] += p0;
      sb[j] += p1;
    }
  float sum0 = (sa[0] + sa[1]) + (sa[2] + sa[3]);
  float sum1 = (sb[0] + sb[1]) + (sb[2] + sb[3]);
  sum0 += __shfl_xor(sum0, 16, 64);
  sum0 += __shfl_xor(sum0, 32, 64);
  sum1 += __shfl_xor(sum1, 16, 64);
  sum1 += __shfl_xor(sum1, 32, 64);
  float inv0 = 1.0f / sum0, inv1 = 1.0f / sum1;

  __syncthreads();  // all K reads done; K region dead -> P slices

  char* pslice = smem + w * 8192;  // wave-private 8KB, reused per tile

  // P-write: unit = (mi>>1)*64 + ((mi&1)*2 + (g>>1))*16 + c16, byte (g&1)*8.
  // PA read (instr ks): unit = ks*64 + lane -> conflict-free.
#define DO_PV(SACC, INV, P)                                                  \
  {                                                                          \
    _Pragma("unroll") for (int mi = 0; mi < 16; ++mi) {                      \
      int un = (mi >> 1) * 64 + ((mi & 1) * 2 + (g >> 1)) * 16 + c16;        \
      uint2 v;                                                               \
      v.x = pack2(SACC[mi][0], SACC[mi][1]);                                 \
      v.y = pack2(SACC[mi][2], SACC[mi][3]);                                 \
      *(uint2*)(pslice + un * 16 + (g & 1) * 8) = v;                         \
    }                                                                        \
    asm volatile("s_waitcnt lgkmcnt(0)" ::: "memory");                       \
    __builtin_amdgcn_sched_barrier(0);                                       \
    f32x4 oacc[4] = {};                                                      \
    _Pragma("unroll") for (int ks = 0; ks < 8; ++ks) {                       \
      bf16x8 pa = *(const bf16x8*)(pslice + (ks * 64 + lane) * 16);          \
      _Pragma("unroll") for (int ni = 0; ni < 4; ++ni) {                     \
        bf16x8 vb = *(const bf16x8*)(smem + 32768 +                          \
                                     ((ks * 4 + ni) * 64 + lane) * 16);      \
        oacc[ni] = __builtin_amdgcn_mfma_f32_16x16x32_bf16(pa, vb,           \
                                                           oacc[ni], 0,0,0); \
      }                                                                      \
    }                                                                        \
    asm volatile("s_waitcnt lgkmcnt(0)" ::: "memory");                       \
    __builtin_amdgcn_sched_barrier(0);                                       \
    _Pragma("unroll") for (int ni = 0; ni < 4; ++ni)                         \
        _Pragma("unroll") for (int j = 0; j < 4; ++j) {                      \
      int row = g * 4 + j, col = ni * 16 + c16;                              \
      int off = (row * 128 + col * 2) ^ ((row & 7) << 4);                    \
      *(bf16*)(pslice + off) = (bf16)(oacc[ni][j] * (INV));                  \
    }                                                                        \
    asm volatile("s_waitcnt lgkmcnt(0)" ::: "memory");                       \
    __builtin_amdgcn_sched_barrier(0);                                       \
    _Pragma("unroll") for (int it = 0; it < 2; ++it) {                       \
      int c = it * 64 + lane;                                                \
      int row = c >> 3, ch = c & 7;                                          \
      int off = (row * 128 + ch * 16) ^ ((row & 7) << 4);                    \
      bf16x8 v = *(const bf16x8*)(pslice + off);                             \
      *(bf16x8*)(O + ((size_t)b * 4096 + n0 + (P) * 64 + w * 16 + row) *     \
                         512 + h * 64 + ch * 8) = v;                         \
    }                                                                        \
    asm volatile("s_waitcnt lgkmcnt(0)" ::: "memory");                       \
    __builtin_amdgcn_sched_barrier(0);                                       \
  }

  DO_PV(sacc0, inv0, 0);
  DO_PV(sacc1, inv1, 1);
#undef DO_PV
}

// ---------------------------------------------------------------------------
extern "C" void kernel_launch(void* const* d_in, const int* in_sizes, int n_in,
                              void* d_out, int out_size, void* d_ws,
                              size_t ws_size, hipStream_t stream) {
  const float* X = (const float*)d_in[0];
  const float* S = (const float*)d_in[1];
  const float* Wq = (const float*)d_in[2];
  const float* Wk = (const float*)d_in[3];
  const float* Wv = (const float*)d_in[4];
  const float* Wo = (const float*)d_in[5];
  const float* temp = (const float*)d_in[6];
  float* out = (float*)d_out;

  char* ws = (char*)d_ws;
  bf16* Ows = (bf16*)ws;                      // 32768*512*2 = 33,554,432 B
  bf16* Kf = (bf16*)(ws + 33554432);          // 64 imgs * 32KB = 2,097,152 B
  bf16* Vf = (bf16*)(ws + 35651584);          // 2,097,152 B
  bf16* Wqb = (bf16*)(ws + 37748736);         // 512*512*2 = 524,288 B each
  bf16* Wkb = (bf16*)(ws + 38273024);
  bf16* Wvb = (bf16*)(ws + 38797312);
  bf16* Wob = (bf16*)(ws + 39321600);

  // d_out scratch (67.1 MB f32), all dead before out_gemm writes:
  //   Xb 32MB @0; Sb 2MB @32M; Qf 32MB @32M (overlaps Sb -- written by the
  //   Q-phase AFTER the KV-phase consumed Sb; kernel boundary serializes).
  bf16* Xb = (bf16*)d_out;                      // 33,554,432 B
  bf16* Sb = (bf16*)((char*)d_out + 33554432);  //  2,097,152 B
  bf16* Qf = (bf16*)((char*)d_out + 33554432);  // 33,554,432 B (ends 67.1MB)

  cvt_all<<<dim3(9216), dim3(256), 0, stream>>>(X, S, Wq, Wk, Wv, Wo, Xb, Sb,
                                                Wqb, Wkb, Wvb, Wob);
  proj_all<1><<<dim3(128), dim3(256), 0, stream>>>(Xb, Sb, Wqb, Wkb, Wvb,
                                                   temp, Qf, Kf, Vf);
  proj_all<0><<<dim3(1024), dim3(256), 0, stream>>>(Xb, Sb, Wqb, Wkb, Wvb,
                                                    temp, Qf, Kf, Vf);
  attn_fused<<<dim3(2048), dim3(256), 0, stream>>>(Qf, Kf, Vf, Ows);
  out_gemm<<<dim3(1024), dim3(256), 0, stream>>>(Ows, Wob, X, out);
}

// Round 21
// 132.678 us; speedup vs baseline: 1.0675x; 1.0675x over previous
//
#include <hip/hip_runtime.h>
#include <hip/hip_bf16.h>

// MDTA (multi-head cross attention with l2-normed q/k) for MI355X.
// B=8, N=4096, Ktok=256, C=512, H=8, D=64. Inputs f32, output f32.
//
// R8 187.9 -> R14 134.9 -> R16 127.6 -> R19 127.7 (attn 42.3) -> R20 141.6
// (QBLK=128 VGPR cliff: 152 regs -> 10% occupancy; reverted).
// R21: attn occupancy via LDS deletion -- K/V fragment images are L2-resident
// and lane-contiguous, so MFMA operands load DIRECTLY global->reg (coalesced
// 1KB loads). No staging, no barriers; LDS = 4x8KB P slices = 32KB -> 5
// blocks/CU (was 2). Waves fully independent.
//
// Pipeline: cvt_all -> proj<KV> -> proj<Q> -> attn_fused -> out_gemm.

typedef __bf16 bf16;
typedef __attribute__((ext_vector_type(8))) __bf16 bf16x8;
typedef __attribute__((ext_vector_type(4))) float f32x4;

#if __has_builtin(__builtin_amdgcn_exp2f)
#define EXP2(x) __builtin_amdgcn_exp2f(x)
#else
#define EXP2(x) exp2f(x)
#endif

__device__ __forceinline__ void gload_lds16(const void* g, void* l) {
  __builtin_amdgcn_global_load_lds(
      (__attribute__((address_space(1))) void*)g,
      (__attribute__((address_space(3))) void*)l, 16, 0, 0);
}

__device__ __forceinline__ unsigned pack2(float a, float b) {
  unsigned short x = __builtin_bit_cast(unsigned short, (bf16)a);
  unsigned short y = __builtin_bit_cast(unsigned short, (bf16)b);
  return (unsigned)x | ((unsigned)y << 16);
}

// ---------------------------------------------------------------------------
// Convert X (2097152 chunks), S (131072), Wq/Wk/Wv/Wo (32768 each) to bf16.
// ---------------------------------------------------------------------------
__global__ __launch_bounds__(256) void cvt_all(
    const float* __restrict__ X, const float* __restrict__ S,
    const float* __restrict__ Wq, const float* __restrict__ Wk,
    const float* __restrict__ Wv, const float* __restrict__ Wo,
    bf16* __restrict__ Xb, bf16* __restrict__ Sb, bf16* __restrict__ Wqb,
    bf16* __restrict__ Wkb, bf16* __restrict__ Wvb, bf16* __restrict__ Wob) {
  int i = blockIdx.x * 256 + threadIdx.x;
  const float* src;
  bf16* dst;
  int r;
  if (i < 2097152) {
    src = X; dst = Xb; r = i;
  } else if (i < 2228224) {
    src = S; dst = Sb; r = i - 2097152;
  } else {
    int j = i - 2228224;
    int w = j >> 15;
    r = j & 32767;
    src = (w == 0) ? Wq : (w == 1) ? Wk : (w == 2) ? Wv : Wo;
    dst = (w == 0) ? Wqb : (w == 1) ? Wkb : (w == 2) ? Wvb : Wob;
  }
  float4 a = *(const float4*)(src + (size_t)r * 8);
  float4 b = *(const float4*)(src + (size_t)r * 8 + 4);
  uint4 v;
  v.x = pack2(a.x, a.y);
  v.y = pack2(a.z, a.w);
  v.z = pack2(b.x, b.y);
  v.w = pack2(b.z, b.w);
  *(uint4*)(dst + (size_t)r * 8) = v;
}

// ---------------------------------------------------------------------------
// Projections. 128x128 tile, BK=32, 16 stages, depth-3 gload_lds pipeline.
// PHASE 0 (grid 1024): Q = l2norm(X@Wq^T)*temp*log2e -> Qfrag images.
// PHASE 1 (grid 128):  Kn = l2norm(S@Wk^T) -> Kfrag; V = S@Wv^T -> Vfrag.
// Fragment image per (b,h): 16B unit u = instr*64 + lane holds
//   Q/K: row (x*16 + lane&15), d-slice (s*32 + (lane>>4)*8), instr = x*2+s
//   V:   V^T row d = ni*16 + (lane&15), t-slice (ks*32 + (lane>>4)*8),
//        instr = ks*4 + ni
// ---------------------------------------------------------------------------
template <int PHASE>
__global__ __launch_bounds__(256) void proj_all(
    const bf16* __restrict__ Xb, const bf16* __restrict__ Sb,
    const bf16* __restrict__ Wqb, const bf16* __restrict__ Wkb,
    const bf16* __restrict__ Wvb, const float* __restrict__ temp,
    bf16* __restrict__ Qf, bf16* __restrict__ Kf, bf16* __restrict__ Vf) {
  __shared__ __align__(16) char smem[49152];  // 3x(As 8KB + Bs 8KB)

  const bf16* A;
  const bf16* W;
  int m0, n0, kind;
  if (PHASE == 0) {
    const int lg = (blockIdx.x & 7) * 128 + (blockIdx.x >> 3);  // 1024
    kind = 0; A = Xb; W = Wqb;
    m0 = (lg >> 2) * 128;
    n0 = (lg & 3) * 128;
  } else {
    const int lg = (blockIdx.x & 7) * 16 + (blockIdx.x >> 3);  // 128
    if (lg < 64) {
      kind = 1; A = Sb; W = Wkb;
      m0 = (lg >> 2) * 128;
      n0 = (lg & 3) * 128;
    } else {
      kind = 2; A = Sb; W = Wvb;
      m0 = ((lg - 64) >> 2) * 128;
      n0 = ((lg - 64) & 3) * 128;
    }
  }

  const int tid = threadIdx.x;
  const int wid = tid >> 6, lane = tid & 63;
  const int wr = wid >> 1, wc = wid & 1;
  const int g = lane >> 4, c16 = lane & 15;
  const int r0 = tid >> 2, cc0 = tid & 3;
  const int r1 = (256 + tid) >> 2, cc1 = tid & 3;
  const int dst0 = (tid & ~63) * 16, dst1 = (256 + (tid & ~63)) * 16;

  f32x4 acc[4][4] = {};

#define PSTAGE(kb, buf)                                                     \
  {                                                                         \
    char* as = smem + (buf) * 8192;                                         \
    char* bs = smem + 24576 + (buf) * 8192;                                 \
    gload_lds16(A + (size_t)(m0 + r0) * 512 + (kb) + cc0 * 8, as + dst0);   \
    gload_lds16(A + (size_t)(m0 + r1) * 512 + (kb) + cc1 * 8, as + dst1);   \
    gload_lds16(W + (size_t)(n0 + r0) * 512 + (kb) + cc0 * 8, bs + dst0);   \
    gload_lds16(W + (size_t)(n0 + r1) * 512 + (kb) + cc1 * 8, bs + dst1);   \
  }

#define PCOMPUTE(buf)                                                       \
  {                                                                         \
    const bf16* as = (const bf16*)(smem + (buf) * 8192);                    \
    const bf16* bs = (const bf16*)(smem + 24576 + (buf) * 8192);            \
    bf16x8 af[4], bfr[4];                                                   \
    _Pragma("unroll") for (int mi = 0; mi < 4; ++mi) af[mi] =               \
        *(const bf16x8*)(as + (wr * 64 + mi * 16 + c16) * 32 + g * 8);      \
    _Pragma("unroll") for (int ni = 0; ni < 4; ++ni) bfr[ni] =              \
        *(const bf16x8*)(bs + (wc * 64 + ni * 16 + c16) * 32 + g * 8);      \
    _Pragma("unroll") for (int mi = 0; mi < 4; ++mi)                        \
        _Pragma("unroll") for (int ni = 0; ni < 4; ++ni) acc[mi][ni] =      \
            __builtin_amdgcn_mfma_f32_16x16x32_bf16(af[mi], bfr[ni],        \
                                                    acc[mi][ni], 0, 0, 0);  \
  }

  PSTAGE(0, 0);
  PSTAGE(32, 1);
  int bufc = 0;
  for (int t = 0; t < 14; ++t) {
    int bufn = bufc + 2;
    if (bufn >= 3) bufn -= 3;
    PSTAGE((t + 2) * 32, bufn);
    asm volatile("s_waitcnt vmcnt(8)" ::: "memory");
    __builtin_amdgcn_s_barrier();
    PCOMPUTE(bufc);
    __builtin_amdgcn_s_barrier();
    if (++bufc == 3) bufc = 0;
  }
  asm volatile("s_waitcnt vmcnt(4)" ::: "memory");
  __builtin_amdgcn_s_barrier();
  PCOMPUTE(bufc);
  __builtin_amdgcn_s_barrier();
  if (++bufc == 3) bufc = 0;
  asm volatile("s_waitcnt vmcnt(0)" ::: "memory");
  __builtin_amdgcn_s_barrier();
  PCOMPUTE(bufc);

  __syncthreads();  // release K-loop LDS for epilogue re-tile

  // ---- epilogue. C/D frag: col = lane&15, row = (lane>>4)*4 + j   [m89]
  if (kind != 2) {
    // l2norm (Q also scaled by temp[h]*log2e) -> LDS re-tile -> fragment img
    const float sc =
        (kind == 0) ? temp[(n0 + wc * 64) >> 6] * 1.44269504088896f : 1.0f;
    char* eps = smem + wid * 8192;  // wave-private 64x64 bf16 tile
#pragma unroll
    for (int mi = 0; mi < 4; ++mi) {
      float ss[4];
#pragma unroll
      for (int j = 0; j < 4; ++j) {
        float s = 0.f;
#pragma unroll
        for (int ni = 0; ni < 4; ++ni) {
          float v = acc[mi][ni][j];
          s += v * v;
        }
        ss[j] = s;
      }
#pragma unroll
      for (int msk = 1; msk < 16; msk <<= 1)
#pragma unroll
        for (int j = 0; j < 4; ++j) ss[j] += __shfl_xor(ss[j], msk, 64);
      float inv[4];
#pragma unroll
      for (int j = 0; j < 4; ++j)
        inv[j] = rsqrtf(fmaxf(ss[j], 1e-24f)) * sc;
#pragma unroll
      for (int ni = 0; ni < 4; ++ni)
#pragma unroll
        for (int j = 0; j < 4; ++j) {
          int row = mi * 16 + g * 4 + j, col = ni * 16 + c16;
          int off = (row * 128 + col * 2) ^ ((row & 7) << 4);
          *(bf16*)(eps + off) = (bf16)(acc[mi][ni][j] * inv[j]);
        }
    }
    asm volatile("s_waitcnt lgkmcnt(0)" ::: "memory");
    __builtin_amdgcn_sched_barrier(0);
#pragma unroll
    for (int it = 0; it < 8; ++it) {
      int c = it * 64 + lane;
      int row = c >> 3, ch = c & 7;
      int off = (row * 128 + ch * 16) ^ ((row & 7) << 4);
      bf16x8 v = *(const bf16x8*)(eps + off);
      int rg = m0 + wr * 64 + row;
      int cg = n0 + wc * 64 + ch * 8;
      int hh = cg >> 6, d0 = cg & 63;
      if (kind == 0) {
        int bb = rg >> 12, qr = rg & 4095;
        int unit = ((qr >> 4) * 2 + (d0 >> 5)) * 64 + ((d0 & 31) >> 3) * 16 +
                   (qr & 15);
        *(bf16x8*)(Qf + (((size_t)(bb * 8 + hh)) << 18) + unit * 8) = v;
      } else {
        int bb = rg >> 8, tt = rg & 255;
        int unit = ((tt >> 4) * 2 + (d0 >> 5)) * 64 + ((d0 & 31) >> 3) * 16 +
                   (tt & 15);
        *(bf16x8*)(Kf + (((size_t)(bb * 8 + hh)) << 14) + unit * 8) = v;
      }
    }
  } else {
    // V fragment store: 4 consecutive tokens at one (h,d) -> 8B into unit
#pragma unroll
    for (int mi = 0; mi < 4; ++mi) {
      int m = m0 + wr * 64 + mi * 16 + g * 4;  // +j
      int bb = m >> 8, tt = m & 255;
#pragma unroll
      for (int ni = 0; ni < 4; ++ni) {
        int col = n0 + wc * 64 + ni * 16 + c16;
        int hh = col >> 6, d = col & 63;
        int unit = ((tt >> 5) * 4 + (d >> 4)) * 64 + ((tt >> 3) & 3) * 16 +
                   (d & 15);
        uint2 v;
        v.x = pack2(acc[mi][ni][0], acc[mi][ni][1]);
        v.y = pack2(acc[mi][ni][2], acc[mi][ni][3]);
        *(uint2*)(Vf + (((size_t)(bb * 8 + hh)) << 14) + unit * 8 +
                  (tt & 7)) = v;
      }
    }
  }
#undef PSTAGE
#undef PCOMPUTE
}

// ---------------------------------------------------------------------------
// out = X + O @ Wo^T, f32 output. Depth-3 pipeline + f32x4 re-tiled epilogue.
// ---------------------------------------------------------------------------
__global__ __launch_bounds__(256) void out_gemm(
    const bf16* __restrict__ O, const bf16* __restrict__ Wob,
    const float* __restrict__ Xres, float* __restrict__ out) {
  __shared__ __align__(16) char smem[49152];

  const int lg = (blockIdx.x & 7) * 128 + (blockIdx.x >> 3);  // XCD swizzle
  const int m0 = (lg >> 2) * 128, n0 = (lg & 3) * 128;

  const int tid = threadIdx.x;
  const int wid = tid >> 6, lane = tid & 63;
  const int wr = wid >> 1, wc = wid & 1;
  const int g = lane >> 4, c16 = lane & 15;
  const int r0 = tid >> 2, cc0 = tid & 3;
  const int r1 = (256 + tid) >> 2, cc1 = tid & 3;
  const int dst0 = (tid & ~63) * 16, dst1 = (256 + (tid & ~63)) * 16;

  f32x4 acc[4][4] = {};

#define OSTAGE(kb, buf)                                                      \
  {                                                                          \
    char* as = smem + (buf) * 8192;                                          \
    char* bs = smem + 24576 + (buf) * 8192;                                  \
    gload_lds16(O + (size_t)(m0 + r0) * 512 + (kb) + cc0 * 8, as + dst0);    \
    gload_lds16(O + (size_t)(m0 + r1) * 512 + (kb) + cc1 * 8, as + dst1);    \
    gload_lds16(Wob + (size_t)(n0 + r0) * 512 + (kb) + cc0 * 8, bs + dst0);  \
    gload_lds16(Wob + (size_t)(n0 + r1) * 512 + (kb) + cc1 * 8, bs + dst1);  \
  }

#define OCOMPUTE(buf)                                                       \
  {                                                                         \
    const bf16* as = (const bf16*)(smem + (buf) * 8192);                    \
    const bf16* bs = (const bf16*)(smem + 24576 + (buf) * 8192);            \
    bf16x8 af[4], bfr[4];                                                   \
    _Pragma("unroll") for (int mi = 0; mi < 4; ++mi) af[mi] =               \
        *(const bf16x8*)(as + (wr * 64 + mi * 16 + c16) * 32 + g * 8);      \
    _Pragma("unroll") for (int ni = 0; ni < 4; ++ni) bfr[ni] =              \
        *(const bf16x8*)(bs + (wc * 64 + ni * 16 + c16) * 32 + g * 8);      \
    _Pragma("unroll") for (int mi = 0; mi < 4; ++mi)                        \
        _Pragma("unroll") for (int ni = 0; ni < 4; ++ni) acc[mi][ni] =      \
            __builtin_amdgcn_mfma_f32_16x16x32_bf16(af[mi], bfr[ni],        \
                                                    acc[mi][ni], 0, 0, 0);  \
  }

  OSTAGE(0, 0);
  OSTAGE(32, 1);
  int bufc = 0;
  for (int t = 0; t < 14; ++t) {
    int bufn = bufc + 2;
    if (bufn >= 3) bufn -= 3;
    OSTAGE((t + 2) * 32, bufn);
    asm volatile("s_waitcnt vmcnt(8)" ::: "memory");
    __builtin_amdgcn_s_barrier();
    OCOMPUTE(bufc);
    __builtin_amdgcn_s_barrier();
    if (++bufc == 3) bufc = 0;
  }
  asm volatile("s_waitcnt vmcnt(4)" ::: "memory");
  __builtin_amdgcn_s_barrier();
  OCOMPUTE(bufc);
  __builtin_amdgcn_s_barrier();
  if (++bufc == 3) bufc = 0;
  asm volatile("s_waitcnt vmcnt(0)" ::: "memory");
  __builtin_amdgcn_s_barrier();
  OCOMPUTE(bufc);

  __syncthreads();  // release K-loop LDS for f32 re-tile

  // Epilogue: 2 passes x (32 rows x 64 cols f32) per wave, swizzled LDS,
  // then float4 X-load + add + float4 store (full-line writes).
  char* eps = smem + wid * 8192;
#pragma unroll
  for (int p = 0; p < 2; ++p) {
#pragma unroll
    for (int mm = 0; mm < 2; ++mm)
#pragma unroll
      for (int ni = 0; ni < 4; ++ni)
#pragma unroll
        for (int j = 0; j < 4; ++j) {
          int row = mm * 16 + g * 4 + j, col = ni * 16 + c16;
          int off = (row * 256 + col * 4) ^ ((row & 7) << 4);
          *(float*)(eps + off) = acc[p * 2 + mm][ni][j];
        }
    asm volatile("s_waitcnt lgkmcnt(0)" ::: "memory");
    __builtin_amdgcn_sched_barrier(0);
#pragma unroll
    for (int it = 0; it < 8; ++it) {
      int c = it * 64 + lane;
      int row = c >> 4, ch = c & 15;
      int off = (row * 256 + ch * 16) ^ ((row & 7) << 4);
      float4 v = *(const float4*)(eps + off);
      size_t gr = (size_t)(m0 + wr * 64 + p * 32 + row) * 512 + n0 +
                  wc * 64 + ch * 4;
      float4 x = *(const float4*)(Xres + gr);
      v.x += x.x;
      v.y += x.y;
      v.z += x.z;
      v.w += x.w;
      *(float4*)(out + gr) = v;
    }
    asm volatile("s_waitcnt lgkmcnt(0)" ::: "memory");
    __builtin_amdgcn_sched_barrier(0);
  }
#undef OSTAGE
#undef OCOMPUTE
}

// ---------------------------------------------------------------------------
// Fused attention, zero-staging variant. Block = (b, h, 64 q-rows), 256 thr
// = 4 waves, 32 KB LDS (only P slices) -> 5 blocks/CU. No __syncthreads.
// K/V MFMA operands load DIRECTLY global->reg from the fragment images
// (lane-contiguous => coalesced 1KB global_load_dwordx4, L2-resident).
// P round-trip through wave-private 8KB slice (lgkm fences only).
// Q pre-scaled by temp*log2e -> exp2 softmax, 1/sum deferred to oacc.
// ---------------------------------------------------------------------------
__global__ __launch_bounds__(256) void attn_fused(
    const bf16* __restrict__ Qf, const bf16* __restrict__ Kf,
    const bf16* __restrict__ Vf, bf16* __restrict__ O) {
  __shared__ __align__(16) char smem[32768];  // 4 x 8KB P slices

  const int tid = threadIdx.x;
  const int w = tid >> 6, lane = tid & 63;
  const int g = lane >> 4, c16 = lane & 15;
  // XCD swizzle: 4096 = 8 XCDs x 512; blocks sharing (b,h) -> same XCD L2.
  const int lg = (blockIdx.x & 7) * 512 + (blockIdx.x >> 3);
  const int nt = lg & 63, h = (lg >> 6) & 7, b = lg >> 9;
  const int n0 = nt * 64;

  const bf16* Kimg = Kf + (((size_t)(b * 8 + h)) << 14);
  const bf16* Vimg = Vf + (((size_t)(b * 8 + h)) << 14);
  const bf16* Qimg = Qf + (((size_t)(b * 8 + h)) << 18);

  // ---- Q fragments (coalesced global loads)
  bf16x8 qf[2];
  {
    int ub = (nt * 4 + w) * 2;
    qf[0] = *(const bf16x8*)(Qimg + (size_t)((ub + 0) * 64 + lane) * 8);
    qf[1] = *(const bf16x8*)(Qimg + (size_t)((ub + 1) * 64 + lane) * 8);
  }

  // ---- S^T = mfma(K, Q^T): kf DIRECT from global (L2). lane holds P[q][k],
  // q = w*16 + c16, k = mi*16 + g*4 + j.
  f32x4 sacc[16] = {};
#pragma unroll
  for (int mi = 0; mi < 16; ++mi) {
#pragma unroll
    for (int s = 0; s < 2; ++s) {
      bf16x8 kf =
          *(const bf16x8*)(Kimg + (size_t)((mi * 2 + s) * 64 + lane) * 8);
      sacc[mi] = __builtin_amdgcn_mfma_f32_16x16x32_bf16(kf, qf[s], sacc[mi],
                                                         0, 0, 0);
    }
  }

  // ---- softmax over k (temp*log2e pre-folded into Q)
  float mx4[4] = {-1e30f, -1e30f, -1e30f, -1e30f};
#pragma unroll
  for (int mi = 0; mi < 16; ++mi)
#pragma unroll
    for (int j = 0; j < 4; ++j) mx4[j] = fmaxf(mx4[j], sacc[mi][j]);
  float mx = fmaxf(fmaxf(mx4[0], mx4[1]), fmaxf(mx4[2], mx4[3]));
  mx = fmaxf(mx, __shfl_xor(mx, 16, 64));
  mx = fmaxf(mx, __shfl_xor(mx, 32, 64));
  float sm4[4] = {0.f, 0.f, 0.f, 0.f};
#pragma unroll
  for (int mi = 0; mi < 16; ++mi)
#pragma unroll
    for (int j = 0; j < 4; ++j) {
      float p = EXP2(sacc[mi][j] - mx);
      sacc[mi][j] = p;
      sm4[j] += p;
    }
  float sum = (sm4[0] + sm4[1]) + (sm4[2] + sm4[3]);
  sum += __shfl_xor(sum, 16, 64);
  sum += __shfl_xor(sum, 32, 64);
  float inv = 1.0f / sum;

  // ---- P -> wave-private slice (fragment layout):
  // unit = (mi>>1)*64 + ((mi&1)*2 + (g>>1))*16 + c16, byte (g&1)*8.
  char* pslice = smem + w * 8192;
#pragma unroll
  for (int mi = 0; mi < 16; ++mi) {
    int un = (mi >> 1) * 64 + ((mi & 1) * 2 + (g >> 1)) * 16 + c16;
    uint2 v;
    v.x = pack2(sacc[mi][0], sacc[mi][1]);
    v.y = pack2(sacc[mi][2], sacc[mi][3]);
    *(uint2*)(pslice + un * 16 + (g & 1) * 8) = v;
  }
  asm volatile("s_waitcnt lgkmcnt(0)" ::: "memory");
  __builtin_amdgcn_sched_barrier(0);

  // ---- O = P @ V: pa from LDS, vb DIRECT from global (L2)
  f32x4 oacc[4] = {};
#pragma unroll
  for (int ks = 0; ks < 8; ++ks) {
    bf16x8 pa = *(const bf16x8*)(pslice + (ks * 64 + lane) * 16);
#pragma unroll
    for (int ni = 0; ni < 4; ++ni) {
      bf16x8 vb =
          *(const bf16x8*)(Vimg + (size_t)((ks * 4 + ni) * 64 + lane) * 8);
      oacc[ni] = __builtin_amdgcn_mfma_f32_16x16x32_bf16(pa, vb, oacc[ni],
                                                         0, 0, 0);
    }
  }
  asm volatile("s_waitcnt lgkmcnt(0)" ::: "memory");
  __builtin_amdgcn_sched_barrier(0);

  // ---- normalize (deferred 1/sum) + O re-tile in own wave's dead P slice
  {
#pragma unroll
    for (int ni = 0; ni < 4; ++ni)
#pragma unroll
      for (int j = 0; j < 4; ++j) {
        int row = g * 4 + j, col = ni * 16 + c16;
        int off = (row * 128 + col * 2) ^ ((row & 7) << 4);
        *(bf16*)(pslice + off) = (bf16)(oacc[ni][j] * inv);
      }
    asm volatile("s_waitcnt lgkmcnt(0)" ::: "memory");
    __builtin_amdgcn_sched_barrier(0);
#pragma unroll
    for (int it = 0; it < 2; ++it) {
      int c = it * 64 + lane;
      int row = c >> 3, ch = c & 7;
      int off = (row * 128 + ch * 16) ^ ((row & 7) << 4);
      bf16x8 v = *(const bf16x8*)(pslice + off);
      *(bf16x8*)(O + ((size_t)b * 4096 + n0 + w * 16 + row) * 512 + h * 64 +
                 ch * 8) = v;
    }
  }
}

// ---------------------------------------------------------------------------
extern "C" void kernel_launch(void* const* d_in, const int* in_sizes, int n_in,
                              void* d_out, int out_size, void* d_ws,
                              size_t ws_size, hipStream_t stream) {
  const float* X = (const float*)d_in[0];
  const float* S = (const float*)d_in[1];
  const float* Wq = (const float*)d_in[2];
  const float* Wk = (const float*)d_in[3];
  const float* Wv = (const float*)d_in[4];
  const float* Wo = (const float*)d_in[5];
  const float* temp = (const float*)d_in[6];
  float* out = (float*)d_out;

  char* ws = (char*)d_ws;
  bf16* Ows = (bf16*)ws;                      // 32768*512*2 = 33,554,432 B
  bf16* Kf = (bf16*)(ws + 33554432);          // 64 imgs * 32KB = 2,097,152 B
  bf16* Vf = (bf16*)(ws + 35651584);          // 2,097,152 B
  bf16* Wqb = (bf16*)(ws + 37748736);         // 512*512*2 = 524,288 B each
  bf16* Wkb = (bf16*)(ws + 38273024);
  bf16* Wvb = (bf16*)(ws + 38797312);
  bf16* Wob = (bf16*)(ws + 39321600);

  // d_out scratch (67.1 MB f32), all dead before out_gemm writes:
  //   Xb 32MB @0; Sb 2MB @32M; Qf 32MB @32M (overlaps Sb -- written by the
  //   Q-phase AFTER the KV-phase consumed Sb; kernel boundary serializes).
  bf16* Xb = (bf16*)d_out;                      // 33,554,432 B
  bf16* Sb = (bf16*)((char*)d_out + 33554432);  //  2,097,152 B
  bf16* Qf = (bf16*)((char*)d_out + 33554432);  // 33,554,432 B (ends 67.1MB)

  cvt_all<<<dim3(9216), dim3(256), 0, stream>>>(X, S, Wq, Wk, Wv, Wo, Xb, Sb,
                                                Wqb, Wkb, Wvb, Wob);
  proj_all<1><<<dim3(128), dim3(256), 0, stream>>>(Xb, Sb, Wqb, Wkb, Wvb,
                                                   temp, Qf, Kf, Vf);
  proj_all<0><<<dim3(1024), dim3(256), 0, stream>>>(Xb, Sb, Wqb, Wkb, Wvb,
                                                    temp, Qf, Kf, Vf);
  attn_fused<<<dim3(4096), dim3(256), 0, stream>>>(Qf, Kf, Vf, Ows);
  out_gemm<<<dim3(1024), dim3(256), 0, stream>>>(Ows, Wob, X, out);
}

// Round 22
// 121.037 us; speedup vs baseline: 1.1701x; 1.0962x over previous
//
#include <hip/hip_runtime.h>
#include <hip/hip_bf16.h>

// MDTA (multi-head cross attention with l2-normed q/k) for MI355X.
// B=8, N=4096, Ktok=256, C=512, H=8, D=64. Inputs f32, output f32.
//
// R8 187.9 -> R14 134.9 -> R16 127.6 -> R19 127.7 (attn 42.3, staged frag
// images) -> R20 141.6 (VGPR cliff) -> R21 132.7 (L2-direct operands slower).
// R22: R19 attn structure, but 512 thr / 8 waves / QBLK=128 per block with
// LDS kept at 64KB: P slices (4KB/wave) overlay the dead K region in TWO
// k-halves (PV accumulates across halves). 2 blocks/CU x 8 waves = 4
// waves/SIMD (2x R19), staging amortized 2x, same per-wave registers.
//
// Pipeline: cvt_all -> proj<KV> -> proj<Q> -> attn_fused -> out_gemm.

typedef __bf16 bf16;
typedef __attribute__((ext_vector_type(8))) __bf16 bf16x8;
typedef __attribute__((ext_vector_type(4))) float f32x4;

#if __has_builtin(__builtin_amdgcn_exp2f)
#define EXP2(x) __builtin_amdgcn_exp2f(x)
#else
#define EXP2(x) exp2f(x)
#endif

__device__ __forceinline__ void gload_lds16(const void* g, void* l) {
  __builtin_amdgcn_global_load_lds(
      (__attribute__((address_space(1))) void*)g,
      (__attribute__((address_space(3))) void*)l, 16, 0, 0);
}

__device__ __forceinline__ unsigned pack2(float a, float b) {
  unsigned short x = __builtin_bit_cast(unsigned short, (bf16)a);
  unsigned short y = __builtin_bit_cast(unsigned short, (bf16)b);
  return (unsigned)x | ((unsigned)y << 16);
}

// ---------------------------------------------------------------------------
// Convert X (2097152 chunks), S (131072), Wq/Wk/Wv/Wo (32768 each) to bf16.
// ---------------------------------------------------------------------------
__global__ __launch_bounds__(256) void cvt_all(
    const float* __restrict__ X, const float* __restrict__ S,
    const float* __restrict__ Wq, const float* __restrict__ Wk,
    const float* __restrict__ Wv, const float* __restrict__ Wo,
    bf16* __restrict__ Xb, bf16* __restrict__ Sb, bf16* __restrict__ Wqb,
    bf16* __restrict__ Wkb, bf16* __restrict__ Wvb, bf16* __restrict__ Wob) {
  int i = blockIdx.x * 256 + threadIdx.x;
  const float* src;
  bf16* dst;
  int r;
  if (i < 2097152) {
    src = X; dst = Xb; r = i;
  } else if (i < 2228224) {
    src = S; dst = Sb; r = i - 2097152;
  } else {
    int j = i - 2228224;
    int w = j >> 15;
    r = j & 32767;
    src = (w == 0) ? Wq : (w == 1) ? Wk : (w == 2) ? Wv : Wo;
    dst = (w == 0) ? Wqb : (w == 1) ? Wkb : (w == 2) ? Wvb : Wob;
  }
  float4 a = *(const float4*)(src + (size_t)r * 8);
  float4 b = *(const float4*)(src + (size_t)r * 8 + 4);
  uint4 v;
  v.x = pack2(a.x, a.y);
  v.y = pack2(a.z, a.w);
  v.z = pack2(b.x, b.y);
  v.w = pack2(b.z, b.w);
  *(uint4*)(dst + (size_t)r * 8) = v;
}

// ---------------------------------------------------------------------------
// Projections. 128x128 tile, BK=32, 16 stages, depth-3 gload_lds pipeline.
// PHASE 0 (grid 1024): Q = l2norm(X@Wq^T)*temp*log2e -> Qfrag images.
// PHASE 1 (grid 128):  Kn = l2norm(S@Wk^T) -> Kfrag; V = S@Wv^T -> Vfrag.
// Fragment image per (b,h): 16B unit u = instr*64 + lane holds
//   Q/K: row (x*16 + lane&15), d-slice (s*32 + (lane>>4)*8), instr = x*2+s
//   V:   V^T row d = ni*16 + (lane&15), t-slice (ks*32 + (lane>>4)*8),
//        instr = ks*4 + ni
// ---------------------------------------------------------------------------
template <int PHASE>
__global__ __launch_bounds__(256) void proj_all(
    const bf16* __restrict__ Xb, const bf16* __restrict__ Sb,
    const bf16* __restrict__ Wqb, const bf16* __restrict__ Wkb,
    const bf16* __restrict__ Wvb, const float* __restrict__ temp,
    bf16* __restrict__ Qf, bf16* __restrict__ Kf, bf16* __restrict__ Vf) {
  __shared__ __align__(16) char smem[49152];  // 3x(As 8KB + Bs 8KB)

  const bf16* A;
  const bf16* W;
  int m0, n0, kind;
  if (PHASE == 0) {
    const int lg = (blockIdx.x & 7) * 128 + (blockIdx.x >> 3);  // 1024
    kind = 0; A = Xb; W = Wqb;
    m0 = (lg >> 2) * 128;
    n0 = (lg & 3) * 128;
  } else {
    const int lg = (blockIdx.x & 7) * 16 + (blockIdx.x >> 3);  // 128
    if (lg < 64) {
      kind = 1; A = Sb; W = Wkb;
      m0 = (lg >> 2) * 128;
      n0 = (lg & 3) * 128;
    } else {
      kind = 2; A = Sb; W = Wvb;
      m0 = ((lg - 64) >> 2) * 128;
      n0 = ((lg - 64) & 3) * 128;
    }
  }

  const int tid = threadIdx.x;
  const int wid = tid >> 6, lane = tid & 63;
  const int wr = wid >> 1, wc = wid & 1;
  const int g = lane >> 4, c16 = lane & 15;
  const int r0 = tid >> 2, cc0 = tid & 3;
  const int r1 = (256 + tid) >> 2, cc1 = tid & 3;
  const int dst0 = (tid & ~63) * 16, dst1 = (256 + (tid & ~63)) * 16;

  f32x4 acc[4][4] = {};

#define PSTAGE(kb, buf)                                                     \
  {                                                                         \
    char* as = smem + (buf) * 8192;                                         \
    char* bs = smem + 24576 + (buf) * 8192;                                 \
    gload_lds16(A + (size_t)(m0 + r0) * 512 + (kb) + cc0 * 8, as + dst0);   \
    gload_lds16(A + (size_t)(m0 + r1) * 512 + (kb) + cc1 * 8, as + dst1);   \
    gload_lds16(W + (size_t)(n0 + r0) * 512 + (kb) + cc0 * 8, bs + dst0);   \
    gload_lds16(W + (size_t)(n0 + r1) * 512 + (kb) + cc1 * 8, bs + dst1);   \
  }

#define PCOMPUTE(buf)                                                       \
  {                                                                         \
    const bf16* as = (const bf16*)(smem + (buf) * 8192);                    \
    const bf16* bs = (const bf16*)(smem + 24576 + (buf) * 8192);            \
    bf16x8 af[4], bfr[4];                                                   \
    _Pragma("unroll") for (int mi = 0; mi < 4; ++mi) af[mi] =               \
        *(const bf16x8*)(as + (wr * 64 + mi * 16 + c16) * 32 + g * 8);      \
    _Pragma("unroll") for (int ni = 0; ni < 4; ++ni) bfr[ni] =              \
        *(const bf16x8*)(bs + (wc * 64 + ni * 16 + c16) * 32 + g * 8);      \
    _Pragma("unroll") for (int mi = 0; mi < 4; ++mi)                        \
        _Pragma("unroll") for (int ni = 0; ni < 4; ++ni) acc[mi][ni] =      \
            __builtin_amdgcn_mfma_f32_16x16x32_bf16(af[mi], bfr[ni],        \
                                                    acc[mi][ni], 0, 0, 0);  \
  }

  PSTAGE(0, 0);
  PSTAGE(32, 1);
  int bufc = 0;
  for (int t = 0; t < 14; ++t) {
    int bufn = bufc + 2;
    if (bufn >= 3) bufn -= 3;
    PSTAGE((t + 2) * 32, bufn);
    asm volatile("s_waitcnt vmcnt(8)" ::: "memory");
    __builtin_amdgcn_s_barrier();
    PCOMPUTE(bufc);
    __builtin_amdgcn_s_barrier();
    if (++bufc == 3) bufc = 0;
  }
  asm volatile("s_waitcnt vmcnt(4)" ::: "memory");
  __builtin_amdgcn_s_barrier();
  PCOMPUTE(bufc);
  __builtin_amdgcn_s_barrier();
  if (++bufc == 3) bufc = 0;
  asm volatile("s_waitcnt vmcnt(0)" ::: "memory");
  __builtin_amdgcn_s_barrier();
  PCOMPUTE(bufc);

  __syncthreads();  // release K-loop LDS for epilogue re-tile

  // ---- epilogue. C/D frag: col = lane&15, row = (lane>>4)*4 + j   [m89]
  if (kind != 2) {
    // l2norm (Q also scaled by temp[h]*log2e) -> LDS re-tile -> fragment img
    const float sc =
        (kind == 0) ? temp[(n0 + wc * 64) >> 6] * 1.44269504088896f : 1.0f;
    char* eps = smem + wid * 8192;  // wave-private 64x64 bf16 tile
#pragma unroll
    for (int mi = 0; mi < 4; ++mi) {
      float ss[4];
#pragma unroll
      for (int j = 0; j < 4; ++j) {
        float s = 0.f;
#pragma unroll
        for (int ni = 0; ni < 4; ++ni) {
          float v = acc[mi][ni][j];
          s += v * v;
        }
        ss[j] = s;
      }
#pragma unroll
      for (int msk = 1; msk < 16; msk <<= 1)
#pragma unroll
        for (int j = 0; j < 4; ++j) ss[j] += __shfl_xor(ss[j], msk, 64);
      float inv[4];
#pragma unroll
      for (int j = 0; j < 4; ++j)
        inv[j] = rsqrtf(fmaxf(ss[j], 1e-24f)) * sc;
#pragma unroll
      for (int ni = 0; ni < 4; ++ni)
#pragma unroll
        for (int j = 0; j < 4; ++j) {
          int row = mi * 16 + g * 4 + j, col = ni * 16 + c16;
          int off = (row * 128 + col * 2) ^ ((row & 7) << 4);
          *(bf16*)(eps + off) = (bf16)(acc[mi][ni][j] * inv[j]);
        }
    }
    asm volatile("s_waitcnt lgkmcnt(0)" ::: "memory");
    __builtin_amdgcn_sched_barrier(0);
#pragma unroll
    for (int it = 0; it < 8; ++it) {
      int c = it * 64 + lane;
      int row = c >> 3, ch = c & 7;
      int off = (row * 128 + ch * 16) ^ ((row & 7) << 4);
      bf16x8 v = *(const bf16x8*)(eps + off);
      int rg = m0 + wr * 64 + row;
      int cg = n0 + wc * 64 + ch * 8;
      int hh = cg >> 6, d0 = cg & 63;
      if (kind == 0) {
        int bb = rg >> 12, qr = rg & 4095;
        int unit = ((qr >> 4) * 2 + (d0 >> 5)) * 64 + ((d0 & 31) >> 3) * 16 +
                   (qr & 15);
        *(bf16x8*)(Qf + (((size_t)(bb * 8 + hh)) << 18) + unit * 8) = v;
      } else {
        int bb = rg >> 8, tt = rg & 255;
        int unit = ((tt >> 4) * 2 + (d0 >> 5)) * 64 + ((d0 & 31) >> 3) * 16 +
                   (tt & 15);
        *(bf16x8*)(Kf + (((size_t)(bb * 8 + hh)) << 14) + unit * 8) = v;
      }
    }
  } else {
    // V fragment store: 4 consecutive tokens at one (h,d) -> 8B into unit
#pragma unroll
    for (int mi = 0; mi < 4; ++mi) {
      int m = m0 + wr * 64 + mi * 16 + g * 4;  // +j
      int bb = m >> 8, tt = m & 255;
#pragma unroll
      for (int ni = 0; ni < 4; ++ni) {
        int col = n0 + wc * 64 + ni * 16 + c16;
        int hh = col >> 6, d = col & 63;
        int unit = ((tt >> 5) * 4 + (d >> 4)) * 64 + ((tt >> 3) & 3) * 16 +
                   (d & 15);
        uint2 v;
        v.x = pack2(acc[mi][ni][0], acc[mi][ni][1]);
        v.y = pack2(acc[mi][ni][2], acc[mi][ni][3]);
        *(uint2*)(Vf + (((size_t)(bb * 8 + hh)) << 14) + unit * 8 +
                  (tt & 7)) = v;
      }
    }
  }
#undef PSTAGE
#undef PCOMPUTE
}

// ---------------------------------------------------------------------------
// out = X + O @ Wo^T, f32 output. Depth-3 pipeline + f32x4 re-tiled epilogue.
// ---------------------------------------------------------------------------
__global__ __launch_bounds__(256) void out_gemm(
    const bf16* __restrict__ O, const bf16* __restrict__ Wob,
    const float* __restrict__ Xres, float* __restrict__ out) {
  __shared__ __align__(16) char smem[49152];

  const int lg = (blockIdx.x & 7) * 128 + (blockIdx.x >> 3);  // XCD swizzle
  const int m0 = (lg >> 2) * 128, n0 = (lg & 3) * 128;

  const int tid = threadIdx.x;
  const int wid = tid >> 6, lane = tid & 63;
  const int wr = wid >> 1, wc = wid & 1;
  const int g = lane >> 4, c16 = lane & 15;
  const int r0 = tid >> 2, cc0 = tid & 3;
  const int r1 = (256 + tid) >> 2, cc1 = tid & 3;
  const int dst0 = (tid & ~63) * 16, dst1 = (256 + (tid & ~63)) * 16;

  f32x4 acc[4][4] = {};

#define OSTAGE(kb, buf)                                                      \
  {                                                                          \
    char* as = smem + (buf) * 8192;                                          \
    char* bs = smem + 24576 + (buf) * 8192;                                  \
    gload_lds16(O + (size_t)(m0 + r0) * 512 + (kb) + cc0 * 8, as + dst0);    \
    gload_lds16(O + (size_t)(m0 + r1) * 512 + (kb) + cc1 * 8, as + dst1);    \
    gload_lds16(Wob + (size_t)(n0 + r0) * 512 + (kb) + cc0 * 8, bs + dst0);  \
    gload_lds16(Wob + (size_t)(n0 + r1) * 512 + (kb) + cc1 * 8, bs + dst1);  \
  }

#define OCOMPUTE(buf)                                                       \
  {                                                                         \
    const bf16* as = (const bf16*)(smem + (buf) * 8192);                    \
    const bf16* bs = (const bf16*)(smem + 24576 + (buf) * 8192);            \
    bf16x8 af[4], bfr[4];                                                   \
    _Pragma("unroll") for (int mi = 0; mi < 4; ++mi) af[mi] =               \
        *(const bf16x8*)(as + (wr * 64 + mi * 16 + c16) * 32 + g * 8);      \
    _Pragma("unroll") for (int ni = 0; ni < 4; ++ni) bfr[ni] =              \
        *(const bf16x8*)(bs + (wc * 64 + ni * 16 + c16) * 32 + g * 8);      \
    _Pragma("unroll") for (int mi = 0; mi < 4; ++mi)                        \
        _Pragma("unroll") for (int ni = 0; ni < 4; ++ni) acc[mi][ni] =      \
            __builtin_amdgcn_mfma_f32_16x16x32_bf16(af[mi], bfr[ni],        \
                                                    acc[mi][ni], 0, 0, 0);  \
  }

  OSTAGE(0, 0);
  OSTAGE(32, 1);
  int bufc = 0;
  for (int t = 0; t < 14; ++t) {
    int bufn = bufc + 2;
    if (bufn >= 3) bufn -= 3;
    OSTAGE((t + 2) * 32, bufn);
    asm volatile("s_waitcnt vmcnt(8)" ::: "memory");
    __builtin_amdgcn_s_barrier();
    OCOMPUTE(bufc);
    __builtin_amdgcn_s_barrier();
    if (++bufc == 3) bufc = 0;
  }
  asm volatile("s_waitcnt vmcnt(4)" ::: "memory");
  __builtin_amdgcn_s_barrier();
  OCOMPUTE(bufc);
  __builtin_amdgcn_s_barrier();
  if (++bufc == 3) bufc = 0;
  asm volatile("s_waitcnt vmcnt(0)" ::: "memory");
  __builtin_amdgcn_s_barrier();
  OCOMPUTE(bufc);

  __syncthreads();  // release K-loop LDS for f32 re-tile

  // Epilogue: 2 passes x (32 rows x 64 cols f32) per wave, swizzled LDS,
  // then float4 X-load + add + float4 store (full-line writes).
  char* eps = smem + wid * 8192;
#pragma unroll
  for (int p = 0; p < 2; ++p) {
#pragma unroll
    for (int mm = 0; mm < 2; ++mm)
#pragma unroll
      for (int ni = 0; ni < 4; ++ni)
#pragma unroll
        for (int j = 0; j < 4; ++j) {
          int row = mm * 16 + g * 4 + j, col = ni * 16 + c16;
          int off = (row * 256 + col * 4) ^ ((row & 7) << 4);
          *(float*)(eps + off) = acc[p * 2 + mm][ni][j];
        }
    asm volatile("s_waitcnt lgkmcnt(0)" ::: "memory");
    __builtin_amdgcn_sched_barrier(0);
#pragma unroll
    for (int it = 0; it < 8; ++it) {
      int c = it * 64 + lane;
      int row = c >> 4, ch = c & 15;
      int off = (row * 256 + ch * 16) ^ ((row & 7) << 4);
      float4 v = *(const float4*)(eps + off);
      size_t gr = (size_t)(m0 + wr * 64 + p * 32 + row) * 512 + n0 +
                  wc * 64 + ch * 4;
      float4 x = *(const float4*)(Xres + gr);
      v.x += x.x;
      v.y += x.y;
      v.z += x.z;
      v.w += x.w;
      *(float4*)(out + gr) = v;
    }
    asm volatile("s_waitcnt lgkmcnt(0)" ::: "memory");
    __builtin_amdgcn_sched_barrier(0);
  }
#undef OSTAGE
#undef OCOMPUTE
}

// ---------------------------------------------------------------------------
// Fused attention. Block = (b, h, 128 q-rows), 512 thr = 8 waves, 64 KB LDS
// -> 2 blocks/CU -> 4 waves/SIMD (2x R19). Wave w owns q rows n0 + w*16.
//   [0,32768)     K frags (32 instr); dead after QK^T -> P slices (4KB/wave,
//                 two k-halves processed sequentially, oacc accumulates)
//   [32768,65536) V frags (32 instr)
// Staging = linear gload_lds from fragment images (coalesced, conflict-free
// lane-contiguous reads). Q direct-to-reg. Only 2 block-wide barriers.
// Q pre-scaled by temp*log2e -> exp2 softmax, 1/sum deferred to oacc.
// ---------------------------------------------------------------------------
__global__ __launch_bounds__(512) void attn_fused(
    const bf16* __restrict__ Qf, const bf16* __restrict__ Kf,
    const bf16* __restrict__ Vf, bf16* __restrict__ O) {
  __shared__ __align__(16) char smem[65536];

  const int tid = threadIdx.x;
  const int w = tid >> 6, lane = tid & 63;
  const int g = lane >> 4, c16 = lane & 15;
  // XCD swizzle: 2048 = 8 XCDs x 256; blocks sharing (b,h) -> same XCD L2.
  const int lg = (blockIdx.x & 7) * 256 + (blockIdx.x >> 3);
  const int nt = lg & 31, h = (lg >> 5) & 7, b = lg >> 8;
  const int n0 = nt * 128;

  const bf16* Kimg = Kf + (((size_t)(b * 8 + h)) << 14);
  const bf16* Vimg = Vf + (((size_t)(b * 8 + h)) << 14);
  const bf16* Qimg = Qf + (((size_t)(b * 8 + h)) << 18);

  // ---- stage K, V: purely linear (fragment images match LDS layout)
#pragma unroll
  for (int it = 0; it < 4; ++it) {
    int base = it * 512 + w * 64;  // wave-uniform 16B-unit base
    gload_lds16(Kimg + (size_t)(base + lane) * 8, smem + base * 16);
    gload_lds16(Vimg + (size_t)(base + lane) * 8, smem + 32768 + base * 16);
  }
  // ---- Q fragments direct to registers (coalesced within image)
  bf16x8 qf[2];
  {
    int ub = (nt * 8 + w) * 2;
    qf[0] = *(const bf16x8*)(Qimg + (size_t)((ub + 0) * 64 + lane) * 8);
    qf[1] = *(const bf16x8*)(Qimg + (size_t)((ub + 1) * 64 + lane) * 8);
  }
  __syncthreads();  // drains gload_lds (vmcnt) + barrier

  // ---- S^T = mfma(K, Q^T): lane holds P[q][k], k = mi*16 + g*4 + j
  f32x4 sacc[16] = {};
#pragma unroll
  for (int mi = 0; mi < 16; ++mi) {
#pragma unroll
    for (int s = 0; s < 2; ++s) {
      bf16x8 kf = *(const bf16x8*)(smem + ((mi * 2 + s) * 64 + lane) * 16);
      sacc[mi] = __builtin_amdgcn_mfma_f32_16x16x32_bf16(kf, qf[s], sacc[mi],
                                                         0, 0, 0);
    }
  }

  // ---- softmax over k (temp*log2e pre-folded into Q)
  float mx4[4] = {-1e30f, -1e30f, -1e30f, -1e30f};
#pragma unroll
  for (int mi = 0; mi < 16; ++mi)
#pragma unroll
    for (int j = 0; j < 4; ++j) mx4[j] = fmaxf(mx4[j], sacc[mi][j]);
  float mx = fmaxf(fmaxf(mx4[0], mx4[1]), fmaxf(mx4[2], mx4[3]));
  mx = fmaxf(mx, __shfl_xor(mx, 16, 64));
  mx = fmaxf(mx, __shfl_xor(mx, 32, 64));
  float sm4[4] = {0.f, 0.f, 0.f, 0.f};
#pragma unroll
  for (int mi = 0; mi < 16; ++mi)
#pragma unroll
    for (int j = 0; j < 4; ++j) {
      float p = EXP2(sacc[mi][j] - mx);
      sacc[mi][j] = p;
      sm4[j] += p;
    }
  float sum = (sm4[0] + sm4[1]) + (sm4[2] + sm4[3]);
  sum += __shfl_xor(sum, 16, 64);
  sum += __shfl_xor(sum, 32, 64);
  float inv = 1.0f / sum;

  __syncthreads();  // all K reads done; K region dead -> P slices (4KB/wave)

  char* pslice = smem + w * 4096;
  f32x4 oacc[4] = {};

  // Two k-halves through the 4KB slice; oacc accumulates across halves.
  // P-write (local frag l = ks - hf*4): unit = l*64 + ((mi&1)*2+(g>>1))*16
  // + c16, byte (g&1)*8, where mi = hf*8 + l*2 + (mi&1).
#pragma unroll
  for (int hf = 0; hf < 2; ++hf) {
#pragma unroll
    for (int ml = 0; ml < 8; ++ml) {
      int mi = hf * 8 + ml;
      int un = (ml >> 1) * 64 + ((ml & 1) * 2 + (g >> 1)) * 16 + c16;
      uint2 v;
      v.x = pack2(sacc[mi][0], sacc[mi][1]);
      v.y = pack2(sacc[mi][2], sacc[mi][3]);
      *(uint2*)(pslice + un * 16 + (g & 1) * 8) = v;
    }
    asm volatile("s_waitcnt lgkmcnt(0)" ::: "memory");
    __builtin_amdgcn_sched_barrier(0);
#pragma unroll
    for (int l = 0; l < 4; ++l) {
      int ks = hf * 4 + l;
      bf16x8 pa = *(const bf16x8*)(pslice + (l * 64 + lane) * 16);
#pragma unroll
      for (int ni = 0; ni < 4; ++ni) {
        bf16x8 vb = *(const bf16x8*)(smem + 32768 +
                                     ((ks * 4 + ni) * 64 + lane) * 16);
        oacc[ni] = __builtin_amdgcn_mfma_f32_16x16x32_bf16(pa, vb, oacc[ni],
                                                           0, 0, 0);
      }
    }
    asm volatile("s_waitcnt lgkmcnt(0)" ::: "memory");
    __builtin_amdgcn_sched_barrier(0);
  }

  // ---- normalize (deferred 1/sum) + O re-tile in own wave's dead P slice
  {
#pragma unroll
    for (int ni = 0; ni < 4; ++ni)
#pragma unroll
      for (int j = 0; j < 4; ++j) {
        int row = g * 4 + j, col = ni * 16 + c16;
        int off = (row * 128 + col * 2) ^ ((row & 7) << 4);
        *(bf16*)(pslice + off) = (bf16)(oacc[ni][j] * inv);
      }
    asm volatile("s_waitcnt lgkmcnt(0)" ::: "memory");
    __builtin_amdgcn_sched_barrier(0);
#pragma unroll
    for (int it = 0; it < 2; ++it) {
      int c = it * 64 + lane;
      int row = c >> 3, ch = c & 7;
      int off = (row * 128 + ch * 16) ^ ((row & 7) << 4);
      bf16x8 v = *(const bf16x8*)(pslice + off);
      *(bf16x8*)(O + ((size_t)b * 4096 + n0 + w * 16 + row) * 512 + h * 64 +
                 ch * 8) = v;
    }
  }
}

// ---------------------------------------------------------------------------
extern "C" void kernel_launch(void* const* d_in, const int* in_sizes, int n_in,
                              void* d_out, int out_size, void* d_ws,
                              size_t ws_size, hipStream_t stream) {
  const float* X = (const float*)d_in[0];
  const float* S = (const float*)d_in[1];
  const float* Wq = (const float*)d_in[2];
  const float* Wk = (const float*)d_in[3];
  const float* Wv = (const float*)d_in[4];
  const float* Wo = (const float*)d_in[5];
  const float* temp = (const float*)d_in[6];
  float* out = (float*)d_out;

  char* ws = (char*)d_ws;
  bf16* Ows = (bf16*)ws;                      // 32768*512*2 = 33,554,432 B
  bf16* Kf = (bf16*)(ws + 33554432);          // 64 imgs * 32KB = 2,097,152 B
  bf16* Vf = (bf16*)(ws + 35651584);          // 2,097,152 B
  bf16* Wqb = (bf16*)(ws + 37748736);         // 512*512*2 = 524,288 B each
  bf16* Wkb = (bf16*)(ws + 38273024);
  bf16* Wvb = (bf16*)(ws + 38797312);
  bf16* Wob = (bf16*)(ws + 39321600);

  // d_out scratch (67.1 MB f32), all dead before out_gemm writes:
  //   Xb 32MB @0; Sb 2MB @32M; Qf 32MB @32M (overlaps Sb -- written by the
  //   Q-phase AFTER the KV-phase consumed Sb; kernel boundary serializes).
  bf16* Xb = (bf16*)d_out;                      // 33,554,432 B
  bf16* Sb = (bf16*)((char*)d_out + 33554432);  //  2,097,152 B
  bf16* Qf = (bf16*)((char*)d_out + 33554432);  // 33,554,432 B (ends 67.1MB)

  cvt_all<<<dim3(9216), dim3(256), 0, stream>>>(X, S, Wq, Wk, Wv, Wo, Xb, Sb,
                                                Wqb, Wkb, Wvb, Wob);
  proj_all<1><<<dim3(128), dim3(256), 0, stream>>>(Xb, Sb, Wqb, Wkb, Wvb,
                                                   temp, Qf, Kf, Vf);
  proj_all<0><<<dim3(1024), dim3(256), 0, stream>>>(Xb, Sb, Wqb, Wkb, Wvb,
                                                    temp, Qf, Kf, Vf);
  attn_fused<<<dim3(2048), dim3(512), 0, stream>>>(Qf, Kf, Vf, Ows);
  out_gemm<<<dim3(1024), dim3(256), 0, stream>>>(Ows, Wob, X, out);
}